// Round 4
// baseline (293.708 us; speedup 1.0000x reference)
//
#include <hip/hip_runtime.h>
#include <hip/hip_bf16.h>

typedef _Float16 halfx8 __attribute__((ext_vector_type(8)));
typedef _Float16 halfx4 __attribute__((ext_vector_type(4)));
typedef _Float16 half2t __attribute__((ext_vector_type(2)));
typedef __fp16 fp16x2 __attribute__((ext_vector_type(2)));
typedef float floatx4 __attribute__((ext_vector_type(4)));

constexpr int S = 2048;
constexpr int DM = 1024;
constexpr int NH = 16;
constexpr int DK = 64;
constexpr int BATCH = 2;
constexpr int MROWS = 4096;
// exp(x) = exp2(x * log2e); fold log2e and 1/sqrt(d_k)=1/8 into Q prescale
constexpr float QSCALE = 0.125f * 1.44269504088896340736f;

#if defined(__has_builtin)
#if __has_builtin(__builtin_amdgcn_fdot2)
#define HAVE_FDOT2 1
#endif
#endif

static __device__ inline half2t pack2(float a, float b) {
  return __builtin_bit_cast(half2t, __builtin_amdgcn_cvt_pkrtz(a, b));
}

// ---------------- weight transpose + fp16 convert: wt[n][k] = (half)w[k][n]
__global__ void convert_w4(const float* __restrict__ w0, const float* __restrict__ w1,
                           const float* __restrict__ w2, const float* __restrict__ w3,
                           _Float16* __restrict__ o0, _Float16* __restrict__ o1,
                           _Float16* __restrict__ o2, _Float16* __restrict__ o3) {
  const float* w = (blockIdx.z == 0) ? w0 : (blockIdx.z == 1) ? w1 : (blockIdx.z == 2) ? w2 : w3;
  _Float16* wt = (blockIdx.z == 0) ? o0 : (blockIdx.z == 1) ? o1 : (blockIdx.z == 2) ? o2 : o3;
  __shared__ float tile[32][33];
  int n0 = blockIdx.x * 32, k0 = blockIdx.y * 32;
  int tx = threadIdx.x, ty = threadIdx.y;  // 32 x 8
#pragma unroll
  for (int i = 0; i < 4; ++i)
    tile[ty + i * 8][tx] = w[(k0 + ty + i * 8) * DM + n0 + tx];
  __syncthreads();
#pragma unroll
  for (int i = 0; i < 4; ++i)
    wt[(n0 + ty + i * 8) * DM + k0 + tx] = (_Float16)tile[tx][ty + i * 8];
}

// ---------------- fp32 -> fp16 elementwise, fused over 3 inputs
__global__ void convert_in3(const float* __restrict__ a0, const float* __restrict__ a1,
                            const float* __restrict__ a2, _Float16* __restrict__ o0,
                            _Float16* __restrict__ o1, _Float16* __restrict__ o2) {
  const float* a = (blockIdx.z == 0) ? a0 : (blockIdx.z == 1) ? a1 : a2;
  _Float16* o = (blockIdx.z == 0) ? o0 : (blockIdx.z == 1) ? o1 : o2;
  size_t i = ((size_t)blockIdx.x * 256 + threadIdx.x) * 8;
  float4 va = *(const float4*)(a + i);
  float4 vb = *(const float4*)(a + i + 4);
  union { halfx8 v; _Float16 h[8]; } u;
  u.h[0] = (_Float16)va.x; u.h[1] = (_Float16)va.y;
  u.h[2] = (_Float16)va.z; u.h[3] = (_Float16)va.w;
  u.h[4] = (_Float16)vb.x; u.h[5] = (_Float16)vb.y;
  u.h[6] = (_Float16)vb.z; u.h[7] = (_Float16)vb.w;
  *(halfx8*)(o + i) = u.v;
}

// ---------------- mask int32 [S][S] -> fp16 {0,1} [S][S]
__global__ void mask_fp16(const int* __restrict__ m, _Float16* __restrict__ Mh) {
  size_t i = ((size_t)blockIdx.x * 256 + threadIdx.x) * 8;
  int4 a = *(const int4*)(m + i);
  int4 b = *(const int4*)(m + i + 4);
  union { halfx8 v; _Float16 h[8]; } u;
  u.h[0] = (_Float16)(a.x != 0); u.h[1] = (_Float16)(a.y != 0);
  u.h[2] = (_Float16)(a.z != 0); u.h[3] = (_Float16)(a.w != 0);
  u.h[4] = (_Float16)(b.x != 0); u.h[5] = (_Float16)(b.y != 0);
  u.h[6] = (_Float16)(b.z != 0); u.h[7] = (_Float16)(b.w != 0);
  *(halfx8*)(Mh + i) = u.v;
}

// ---------------- fused QKV GEMM: [4096 x 3072] = A_w[4096x1024] * wqkv[3072x1024]^T
// 128x128 block tile, 4 waves of 64x64. N blocks 0..7 -> Q (scaled), 8..15 -> K,
// 16..23 -> V (transposed store to Vt[B,H,DK,S]).
__global__ __launch_bounds__(256) void qkv_gemm(const _Float16* __restrict__ xq,
                                                const _Float16* __restrict__ xk,
                                                const _Float16* __restrict__ xv,
                                                const _Float16* __restrict__ wqkv,
                                                _Float16* __restrict__ Qh,
                                                _Float16* __restrict__ Kh,
                                                _Float16* __restrict__ Vt) {
  constexpr int LDT = 72;
  __shared__ __align__(16) _Float16 smem[2 * 128 * LDT];
  _Float16* Asm = smem;
  _Float16* Bsm = smem + 128 * LDT;
  const int tid = threadIdx.x;
  const int w = tid >> 6, l = tid & 63, lo = l & 15, quad = l >> 4;
  const int wm = (w >> 1) * 64, wn = (w & 1) * 64;
  const int bx = blockIdx.x, bm = blockIdx.y * 128;
  const int wid = bx >> 3;
  const _Float16* A = (wid == 0) ? xq : (wid == 1) ? xk : xv;
  const _Float16* Bt = wqkv + (size_t)bx * 128 * DM;

  const int srow = tid >> 1, scol = (tid & 1) * 32;
  const _Float16* Aptr = A + (size_t)(bm + srow) * DM + scol;
  const _Float16* Bptr = Bt + (size_t)srow * DM + scol;

  floatx4 acc[4][4] = {};

  for (int k0 = 0; k0 < DM; k0 += 64) {
#pragma unroll
    for (int i = 0; i < 4; ++i)
      *(halfx8*)&Asm[srow * LDT + scol + i * 8] = *(const halfx8*)(Aptr + k0 + i * 8);
#pragma unroll
    for (int i = 0; i < 4; ++i)
      *(halfx8*)&Bsm[srow * LDT + scol + i * 8] = *(const halfx8*)(Bptr + k0 + i * 8);
    __syncthreads();

#pragma unroll
    for (int ks = 0; ks < 2; ++ks) {
      halfx8 af[4], bf[4];
#pragma unroll
      for (int mt = 0; mt < 4; ++mt)
        af[mt] = *(const halfx8*)&Asm[(wm + mt * 16 + lo) * LDT + ks * 32 + quad * 8];
#pragma unroll
      for (int nt = 0; nt < 4; ++nt)
        bf[nt] = *(const halfx8*)&Bsm[(wn + nt * 16 + lo) * LDT + ks * 32 + quad * 8];
#pragma unroll
      for (int mt = 0; mt < 4; ++mt)
#pragma unroll
        for (int nt = 0; nt < 4; ++nt)
          acc[mt][nt] =
              __builtin_amdgcn_mfma_f32_16x16x32_f16(af[mt], bf[nt], acc[mt][nt], 0, 0, 0);
    }
    __syncthreads();
  }

  if (wid == 2) {
    // V: transpose 128(s) x 128(d) tile through LDS, coalesced b128 stores
    constexpr int LDTT = 136;
    _Float16* tb = smem;  // 128*136 = 17408 halves <= 2*128*72
#pragma unroll
    for (int mt = 0; mt < 4; ++mt)
#pragma unroll
      for (int nt = 0; nt < 4; ++nt)
#pragma unroll
        for (int r = 0; r < 4; ++r) {
          int dl = wn + nt * 16 + lo;             // d within [0,128)
          int sl = wm + mt * 16 + quad * 4 + r;   // s within [0,128)
          tb[dl * LDTT + sl] = (_Float16)acc[mt][nt][r];
        }
    __syncthreads();
    const int b = bm >> 11, s0 = bm & (S - 1);
    const int d2 = tid >> 1, chunk = (tid & 1) * 64;
    const int dg = ((bx & 7) * 128 + d2);
    const int h = dg >> 6, dd = dg & 63;
    _Float16* O = Vt + ((size_t)(b * NH + h) * DK + dd) * S + s0 + chunk;
#pragma unroll
    for (int j = 0; j < 8; ++j)
      *(halfx8*)(O + j * 8) = *(const halfx8*)&tb[d2 * LDTT + chunk + j * 8];
    return;
  }

  _Float16* Out = (wid == 0) ? Qh : Kh;
  const float scale = (wid == 0) ? QSCALE : 1.0f;
#pragma unroll
  for (int mt = 0; mt < 4; ++mt)
#pragma unroll
    for (int nt = 0; nt < 4; ++nt)
#pragma unroll
      for (int r = 0; r < 4; ++r) {
        int row = bm + wm + mt * 16 + quad * 4 + r;
        int n = (bx & 7) * 128 + wn + nt * 16 + lo;
        int b = row >> 11, s = row & (S - 1);
        int h = n >> 6, d = n & 63;
        Out[((size_t)(b * NH + h) * S + s) * DK + d] = (_Float16)(acc[mt][nt][r] * scale);
      }
}

// ---------------- flash attention, operand-swapped (query on lane&15)
// Q[B,H,S,DK] prescaled by 0.125*log2e; K[B,H,S,DK]; Vt[B,H,DK,S]; Mh[S][S] fp16 {0,1}
__global__ __launch_bounds__(256) void attn_kernel(const _Float16* __restrict__ Q,
                                                   const _Float16* __restrict__ Kh,
                                                   const _Float16* __restrict__ Vt,
                                                   const _Float16* __restrict__ Mh,
                                                   _Float16* __restrict__ concat) {
  constexpr int LDT = 72;
  __shared__ __align__(16) _Float16 Ksm[64 * LDT];
  __shared__ __align__(16) _Float16 Vsm[64 * LDT];
  __shared__ __align__(16) _Float16 Psm[4 * 16 * LDT];

  const int tid = threadIdx.x;
  const int w = tid >> 6, l = tid & 63, lo = l & 15, quad = l >> 4;
  const int qb = blockIdx.x * 64 + w * 16;  // wave's 16 q-rows
  const int h = blockIdx.y, b = blockIdx.z;

  const _Float16* Qb = Q + (size_t)(b * NH + h) * S * DK;
  const _Float16* Kb = Kh + (size_t)(b * NH + h) * S * DK;
  const _Float16* Vb = Vt + (size_t)(b * NH + h) * DK * S;
  const _Float16* Mq = Mh + (size_t)(qb + lo) * S;  // this lane's query row

  halfx8 qf[2];
#pragma unroll
  for (int ks = 0; ks < 2; ++ks)
    qf[ks] = *(const halfx8*)(Qb + (qb + lo) * DK + ks * 32 + quad * 8);

  floatx4 Oacc[4] = {};
  float lsum = 0.f;
  const half2t onev = {(_Float16)1.0f, (_Float16)1.0f};

  const int srow = tid >> 2, scol = (tid & 3) * 16;
  const _Float16* Kp = Kb + srow * DK + scol;
  const _Float16* Vp = Vb + srow * S + scol;
  _Float16* Pw = &Psm[w * 16 * LDT];

  for (int kt = 0; kt < S / 64; ++kt) {
#pragma unroll
    for (int i = 0; i < 2; ++i) {
      *(halfx8*)&Ksm[srow * LDT + scol + i * 8] = *(const halfx8*)(Kp + kt * 64 * DK + i * 8);
      *(halfx8*)&Vsm[srow * LDT + scol + i * 8] = *(const halfx8*)(Vp + kt * 64 + i * 8);
    }
    __syncthreads();

    // S^T = K Q^T : D row = key (quad*4+r), col = query (lane&15)
    floatx4 Sacc[4] = {};
#pragma unroll
    for (int ks = 0; ks < 2; ++ks)
#pragma unroll
      for (int nt = 0; nt < 4; ++nt) {
        halfx8 kf = *(const halfx8*)&Ksm[(nt * 16 + lo) * LDT + ks * 32 + quad * 8];
        Sacc[nt] = __builtin_amdgcn_mfma_f32_16x16x32_f16(kf, qf[ks], Sacc[nt], 0, 0, 0);
      }

    // exp2 + fp16 mask multiply + packed row-sum + P store (query-major rows)
#pragma unroll
    for (int nt = 0; nt < 4; ++nt) {
      union { halfx4 v; half2t h[2]; } mv;
      mv.v = *(const halfx4*)(Mq + kt * 64 + nt * 16 + quad * 4);
      half2t p01 = pack2(__builtin_exp2f(Sacc[nt][0]), __builtin_exp2f(Sacc[nt][1]));
      half2t p23 = pack2(__builtin_exp2f(Sacc[nt][2]), __builtin_exp2f(Sacc[nt][3]));
      p01 *= mv.h[0];
      p23 *= mv.h[1];
#ifdef HAVE_FDOT2
      lsum = __builtin_amdgcn_fdot2(__builtin_bit_cast(fp16x2, p01),
                                    __builtin_bit_cast(fp16x2, onev), lsum, false);
      lsum = __builtin_amdgcn_fdot2(__builtin_bit_cast(fp16x2, p23),
                                    __builtin_bit_cast(fp16x2, onev), lsum, false);
#else
      lsum += (float)p01[0] + (float)p01[1] + (float)p23[0] + (float)p23[1];
#endif
      union { halfx4 v; half2t h[2]; } u;
      u.h[0] = p01; u.h[1] = p23;
      *(halfx4*)&Pw[lo * LDT + nt * 16 + quad * 4] = u.v;
    }

    // O += P V : A = P (query rows), B = V^T (d rows); same-wave LDS, no barrier
#pragma unroll
    for (int ks = 0; ks < 2; ++ks) {
      halfx8 pf = *(const halfx8*)&Pw[lo * LDT + ks * 32 + quad * 8];
#pragma unroll
      for (int nt = 0; nt < 4; ++nt) {
        halfx8 vf = *(const halfx8*)&Vsm[(nt * 16 + lo) * LDT + ks * 32 + quad * 8];
        Oacc[nt] = __builtin_amdgcn_mfma_f32_16x16x32_f16(pf, vf, Oacc[nt], 0, 0, 0);
      }
    }
    __syncthreads();
  }

  // reduce per-lane partial row-sums across the 4 quads (same query = same lo)
  lsum += __shfl_xor(lsum, 16);
  lsum += __shfl_xor(lsum, 32);

#pragma unroll
  for (int r = 0; r < 4; ++r) {
    float lr = __shfl(lsum, quad * 4 + r);  // lane (quad*4+r) holds query qb+quad*4+r
    float inv = __builtin_amdgcn_rcpf(lr);
    int q = qb + quad * 4 + r;
#pragma unroll
    for (int nt = 0; nt < 4; ++nt) {
      int d = nt * 16 + lo;
      concat[((size_t)b * S + q) * DM + h * DK + d] = (_Float16)(Oacc[nt][r] * inv);
    }
  }
}

// ---------------- output GEMM: out[4096x1024] = concat * wto^T + bias (fp32 out)
__global__ __launch_bounds__(256) void out_gemm(const _Float16* __restrict__ A,
                                                const _Float16* __restrict__ Bt,
                                                float* __restrict__ Cp,
                                                const float* __restrict__ bias) {
  constexpr int LDT = 72;
  __shared__ __align__(16) _Float16 Asm[128 * LDT];
  __shared__ __align__(16) _Float16 Bsm[64 * LDT];
  const int tid = threadIdx.x;
  const int w = tid >> 6, l = tid & 63, lo = l & 15, quad = l >> 4;
  const int wm = (w >> 1) * 64, wn = (w & 1) * 32;
  const int bm = blockIdx.y * 128, bn = blockIdx.x * 64;

  const int arow = tid >> 1, acol = (tid & 1) * 32;
  const int brow = tid >> 2, bcol = (tid & 3) * 16;

  floatx4 acc[4][2] = {};

  for (int k0 = 0; k0 < DM; k0 += 64) {
#pragma unroll
    for (int i = 0; i < 4; ++i)
      *(halfx8*)&Asm[arow * LDT + acol + i * 8] =
          *(const halfx8*)(A + (size_t)(bm + arow) * DM + k0 + acol + i * 8);
#pragma unroll
    for (int i = 0; i < 2; ++i)
      *(halfx8*)&Bsm[brow * LDT + bcol + i * 8] =
          *(const halfx8*)(Bt + (size_t)(bn + brow) * DM + k0 + bcol + i * 8);
    __syncthreads();

#pragma unroll
    for (int ks = 0; ks < 2; ++ks) {
      halfx8 af[4], bfr[2];
#pragma unroll
      for (int mt = 0; mt < 4; ++mt)
        af[mt] = *(const halfx8*)&Asm[(wm + mt * 16 + lo) * LDT + ks * 32 + quad * 8];
#pragma unroll
      for (int nt = 0; nt < 2; ++nt)
        bfr[nt] = *(const halfx8*)&Bsm[(wn + nt * 16 + lo) * LDT + ks * 32 + quad * 8];
#pragma unroll
      for (int mt = 0; mt < 4; ++mt)
#pragma unroll
        for (int nt = 0; nt < 2; ++nt)
          acc[mt][nt] =
              __builtin_amdgcn_mfma_f32_16x16x32_f16(af[mt], bfr[nt], acc[mt][nt], 0, 0, 0);
    }
    __syncthreads();
  }

#pragma unroll
  for (int mt = 0; mt < 4; ++mt)
#pragma unroll
    for (int nt = 0; nt < 2; ++nt)
#pragma unroll
      for (int r = 0; r < 4; ++r) {
        int row = bm + wm + mt * 16 + quad * 4 + r;
        int col = bn + wn + nt * 16 + lo;
        Cp[(size_t)row * DM + col] = acc[mt][nt][r] + bias[col];
      }
}

extern "C" void kernel_launch(void* const* d_in, const int* in_sizes, int n_in,
                              void* d_out, int out_size, void* d_ws, size_t ws_size,
                              hipStream_t stream) {
  const float* in_q = (const float*)d_in[0];
  const float* in_k = (const float*)d_in[1];
  const float* in_v = (const float*)d_in[2];
  const int* mask = (const int*)d_in[3];
  const float* w_q = (const float*)d_in[4];
  const float* w_k = (const float*)d_in[5];
  const float* w_v = (const float*)d_in[6];
  const float* w_o = (const float*)d_in[7];
  const float* b_o = (const float*)d_in[8];
  float* out = (float*)d_out;

  char* ws = (char*)d_ws;
  constexpr size_t WB = (size_t)DM * DM * sizeof(_Float16);   // 2 MiB per weight
  constexpr size_t MB_ = (size_t)S * S * sizeof(_Float16);    // 8 MiB fp16 mask
  constexpr size_t TB = (size_t)MROWS * DM * sizeof(_Float16);// 8 MiB per tensor
  _Float16* wqkv = (_Float16*)(ws);                  // 6 MiB: wtq|wtk|wtv
  _Float16* wto = (_Float16*)(ws + 3 * WB);          // 2 MiB
  _Float16* Mh = (_Float16*)(ws + 4 * WB);           // 8 MiB
  char* p = ws + 4 * WB + MB_;
  _Float16* Qh = (_Float16*)(p);
  _Float16* Kh = (_Float16*)(p + TB);
  _Float16* Vt = (_Float16*)(p + 2 * TB);
  _Float16* xq = (_Float16*)(p + 3 * TB);
  _Float16* xk = (_Float16*)(p + 4 * TB);
  _Float16* xv = (_Float16*)(p + 5 * TB);
  _Float16* concat = xq;  // xq dead after qkv_gemm; attn writes concat there
  // total ws use: 16 MiB + 6*8 MiB = 64 MiB

  convert_w4<<<dim3(32, 32, 4), dim3(32, 8), 0, stream>>>(
      w_q, w_k, w_v, w_o, wqkv, wqkv + DM * DM, wqkv + 2 * DM * DM, wto);
  convert_in3<<<dim3(MROWS * DM / 8 / 256, 1, 3), 256, 0, stream>>>(in_q, in_k, in_v,
                                                                    xq, xk, xv);
  mask_fp16<<<dim3(S * S / 8 / 256), 256, 0, stream>>>(mask, Mh);

  qkv_gemm<<<dim3(24, 32), 256, 0, stream>>>(xq, xk, xv, wqkv, Qh, Kh, Vt);
  attn_kernel<<<dim3(S / 64, NH, BATCH), 256, 0, stream>>>(Qh, Kh, Vt, Mh, concat);
  out_gemm<<<dim3(DM / 64, MROWS / 128), 256, 0, stream>>>(concat, wto, out, b_o);
}

// Round 5
// 266.251 us; speedup vs baseline: 1.1031x; 1.1031x over previous
//
#include <hip/hip_runtime.h>
#include <hip/hip_bf16.h>

typedef _Float16 halfx8 __attribute__((ext_vector_type(8)));
typedef _Float16 halfx4 __attribute__((ext_vector_type(4)));
typedef _Float16 half2t __attribute__((ext_vector_type(2)));
typedef __fp16 fp16x2 __attribute__((ext_vector_type(2)));
typedef float floatx4 __attribute__((ext_vector_type(4)));

constexpr int S = 2048;
constexpr int DM = 1024;
constexpr int NH = 16;
constexpr int DK = 64;
constexpr int BATCH = 2;
constexpr int MROWS = 4096;
// exp(x) = exp2(x * log2e); fold log2e and 1/sqrt(d_k)=1/8 into Q prescale
constexpr float QSCALE = 0.125f * 1.44269504088896340736f;

#if defined(__has_builtin)
#if __has_builtin(__builtin_amdgcn_fdot2)
#define HAVE_FDOT2 1
#endif
#endif

static __device__ inline half2t pack2(float a, float b) {
  return __builtin_bit_cast(half2t, __builtin_amdgcn_cvt_pkrtz(a, b));
}

// async 16B global -> LDS (wave-uniform base + lane*16; lane order = chunk order)
static __device__ inline void load_lds16(const _Float16* g, _Float16* l) {
  __builtin_amdgcn_global_load_lds((const __attribute__((address_space(1))) void*)g,
                                   (__attribute__((address_space(3))) void*)l, 16, 0, 0);
}

// ---------------- weight transpose + fp16 convert: wt[n][k] = (half)w[k][n]
__global__ void convert_w4(const float* __restrict__ w0, const float* __restrict__ w1,
                           const float* __restrict__ w2, const float* __restrict__ w3,
                           _Float16* __restrict__ o0, _Float16* __restrict__ o1,
                           _Float16* __restrict__ o2, _Float16* __restrict__ o3) {
  const float* w = (blockIdx.z == 0) ? w0 : (blockIdx.z == 1) ? w1 : (blockIdx.z == 2) ? w2 : w3;
  _Float16* wt = (blockIdx.z == 0) ? o0 : (blockIdx.z == 1) ? o1 : (blockIdx.z == 2) ? o2 : o3;
  __shared__ float tile[32][33];
  int n0 = blockIdx.x * 32, k0 = blockIdx.y * 32;
  int tx = threadIdx.x, ty = threadIdx.y;  // 32 x 8
#pragma unroll
  for (int i = 0; i < 4; ++i)
    tile[ty + i * 8][tx] = w[(k0 + ty + i * 8) * DM + n0 + tx];
  __syncthreads();
#pragma unroll
  for (int i = 0; i < 4; ++i)
    wt[(n0 + ty + i * 8) * DM + k0 + tx] = (_Float16)tile[tx][ty + i * 8];
}

// ---------------- fp32 -> fp16 elementwise, fused over 3 inputs
__global__ void convert_in3(const float* __restrict__ a0, const float* __restrict__ a1,
                            const float* __restrict__ a2, _Float16* __restrict__ o0,
                            _Float16* __restrict__ o1, _Float16* __restrict__ o2) {
  const float* a = (blockIdx.z == 0) ? a0 : (blockIdx.z == 1) ? a1 : a2;
  _Float16* o = (blockIdx.z == 0) ? o0 : (blockIdx.z == 1) ? o1 : o2;
  size_t i = ((size_t)blockIdx.x * 256 + threadIdx.x) * 8;
  float4 va = *(const float4*)(a + i);
  float4 vb = *(const float4*)(a + i + 4);
  union { halfx8 v; _Float16 h[8]; } u;
  u.h[0] = (_Float16)va.x; u.h[1] = (_Float16)va.y;
  u.h[2] = (_Float16)va.z; u.h[3] = (_Float16)va.w;
  u.h[4] = (_Float16)vb.x; u.h[5] = (_Float16)vb.y;
  u.h[6] = (_Float16)vb.z; u.h[7] = (_Float16)vb.w;
  *(halfx8*)(o + i) = u.v;
}

// ---------------- mask -> swizzled fp16 tiles Mt[kt][q][quad][16]
// half j (=nt*4+r) of (kt,q,quad) = (mask[q][kt*64 + nt*16 + quad*4 + r] != 0)
__global__ void mask_swz(const int* __restrict__ m, _Float16* __restrict__ Mt) {
  int t = blockIdx.x * 256 + threadIdx.x;
  int j0 = (t & 1) * 8;          // halves j0..j0+7 -> nt0 = j0>>2, nt0+1
  int quad = (t >> 1) & 3;
  int q = (t >> 3) & (S - 1);
  int kt = t >> 14;
  const int* src = m + (size_t)q * S + kt * 64 + (j0 >> 2) * 16 + quad * 4;
  int4 a = *(const int4*)src;
  int4 b = *(const int4*)(src + 16);
  union { halfx8 v; _Float16 h[8]; } u;
  u.h[0] = (_Float16)(a.x != 0); u.h[1] = (_Float16)(a.y != 0);
  u.h[2] = (_Float16)(a.z != 0); u.h[3] = (_Float16)(a.w != 0);
  u.h[4] = (_Float16)(b.x != 0); u.h[5] = (_Float16)(b.y != 0);
  u.h[6] = (_Float16)(b.z != 0); u.h[7] = (_Float16)(b.w != 0);
  *(halfx8*)(Mt + (size_t)t * 8) = u.v;
}

// ---------------- fused QKV GEMM: [4096 x 3072] = x[4096x1024] * wqkv[3072x1024]^T
// 128x128 block tile, 4 waves of 64x64, global_load_lds staging, XOR-swizzled LDS.
// bx 0..7 -> Q flat (scaled), 8..15 -> K flat, 16..23 -> V transposed [B,H,DK,S].
__global__ __launch_bounds__(256) void qkv_gemm(const _Float16* __restrict__ xq,
                                                const _Float16* __restrict__ xk,
                                                const _Float16* __restrict__ xv,
                                                const _Float16* __restrict__ wqkv,
                                                _Float16* __restrict__ Qf,
                                                _Float16* __restrict__ Kf,
                                                _Float16* __restrict__ Vt) {
  __shared__ __align__(16) _Float16 smem[17408];  // staging 16384; V-transpose 17408
  _Float16* Asm = smem;                // 128 rows x 8 chunks (chunk = 8 halves)
  _Float16* Bsm = smem + 128 * 64;
  const int tid = threadIdx.x;
  const int w = tid >> 6, l = tid & 63, lo = l & 15, quad = l >> 4;
  const int lo7 = l & 7;
  const int wm = (w >> 1) * 64, wn = (w & 1) * 64;
  const int bx = blockIdx.x, bm = blockIdx.y * 128;
  const int wid = bx >> 3;
  const _Float16* A = (wid == 0) ? xq : (wid == 1) ? xk : xv;
  const _Float16* Bt = wqkv + (size_t)bx * 128 * DM;

  floatx4 acc[4][4] = {};

  for (int k0 = 0; k0 < DM; k0 += 64) {
#pragma unroll
    for (int i = 0; i < 4; ++i) {
      int chunk = i * 256 + tid;            // 1024 chunks = 128 rows x 8
      int r = chunk >> 3;
      int c = (chunk & 7) ^ (r & 7);        // logical chunk for this physical slot
      load_lds16(A + (size_t)(bm + r) * DM + k0 + c * 8, Asm + chunk * 8);
    }
#pragma unroll
    for (int i = 0; i < 4; ++i) {
      int chunk = i * 256 + tid;
      int r = chunk >> 3;
      int c = (chunk & 7) ^ (r & 7);
      load_lds16(Bt + (size_t)r * DM + k0 + c * 8, Bsm + chunk * 8);
    }
    __syncthreads();

#pragma unroll
    for (int ks = 0; ks < 2; ++ks) {
      halfx8 af[4], bf[4];
#pragma unroll
      for (int mt = 0; mt < 4; ++mt)
        af[mt] = *(const halfx8*)&Asm[(wm + mt * 16 + lo) * 64 + (((ks * 4 + quad) ^ lo7) * 8)];
#pragma unroll
      for (int nt = 0; nt < 4; ++nt)
        bf[nt] = *(const halfx8*)&Bsm[(wn + nt * 16 + lo) * 64 + (((ks * 4 + quad) ^ lo7) * 8)];
#pragma unroll
      for (int mt = 0; mt < 4; ++mt)
#pragma unroll
        for (int nt = 0; nt < 4; ++nt)
          acc[mt][nt] =
              __builtin_amdgcn_mfma_f32_16x16x32_f16(af[mt], bf[nt], acc[mt][nt], 0, 0, 0);
    }
    __syncthreads();
  }

  if (wid == 2) {
    // V: transpose 128(s) x 128(d) tile through LDS, coalesced b128 stores
    constexpr int LDTT = 136;
    _Float16* tb = smem;  // 128*136 = 17408 halves
#pragma unroll
    for (int mt = 0; mt < 4; ++mt)
#pragma unroll
      for (int nt = 0; nt < 4; ++nt)
#pragma unroll
        for (int r = 0; r < 4; ++r) {
          int dl = wn + nt * 16 + lo;             // d within [0,128)
          int sl = wm + mt * 16 + quad * 4 + r;   // s within [0,128)
          tb[dl * LDTT + sl] = (_Float16)acc[mt][nt][r];
        }
    __syncthreads();
    const int b = bm >> 11, s0 = bm & (S - 1);
    const int d2 = tid >> 1, chunk = (tid & 1) * 64;
    const int dg = ((bx & 7) * 128 + d2);
    const int h = dg >> 6, dd = dg & 63;
    _Float16* O = Vt + ((size_t)(b * NH + h) * DK + dd) * S + s0 + chunk;
#pragma unroll
    for (int j = 0; j < 8; ++j)
      *(halfx8*)(O + j * 8) = *(const halfx8*)&tb[d2 * LDTT + chunk + j * 8];
    return;
  }

  // Q/K: flat [4096][1024] layout, attn handles head offsets
  _Float16* Out = (wid == 0) ? Qf : Kf;
  const float scale = (wid == 0) ? QSCALE : 1.0f;
#pragma unroll
  for (int mt = 0; mt < 4; ++mt)
#pragma unroll
    for (int nt = 0; nt < 4; ++nt)
#pragma unroll
      for (int r = 0; r < 4; ++r) {
        int row = bm + wm + mt * 16 + quad * 4 + r;
        int col = (bx & 7) * 128 + wn + nt * 16 + lo;
        Out[(size_t)row * DM + col] = (_Float16)(acc[mt][nt][r] * scale);
      }
}

// ---------------- flash attention, operand-swapped, swizzled LDS + async staging
// Qf/Kf flat [4096][1024] (Q prescaled 0.125*log2e); Vt[B,H,DK,S]; Mt swizzled tiles
__global__ __launch_bounds__(256) void attn_kernel(const _Float16* __restrict__ Qf,
                                                   const _Float16* __restrict__ Kf,
                                                   const _Float16* __restrict__ Vt,
                                                   const _Float16* __restrict__ Mt,
                                                   _Float16* __restrict__ concat) {
  __shared__ __align__(16) _Float16 Ksm[64 * 64];   // [key][d], swizzled
  __shared__ __align__(16) _Float16 Vsm[64 * 64];   // [d][key], swizzled
  __shared__ __align__(16) _Float16 Psm[4 * 16 * 64];  // per-wave [q][key], swizzled

  const int tid = threadIdx.x;
  const int w = tid >> 6, l = tid & 63, lo = l & 15, quad = l >> 4;
  const int lo7 = l & 7;
  const int qb = blockIdx.x * 64 + w * 16;  // wave's 16 q-rows
  const int h = blockIdx.y, b = blockIdx.z;

  const _Float16* Vb = Vt + (size_t)(b * NH + h) * DK * S;
  const _Float16* Mw = Mt + ((size_t)(qb + lo) * 4 + quad) * 16;  // + kt*131072

  halfx8 qf[2];
#pragma unroll
  for (int ks = 0; ks < 2; ++ks)
    qf[ks] = *(const halfx8*)(Qf + ((size_t)b * S + qb + lo) * DM + h * DK + ks * 32 + quad * 8);

  floatx4 Oacc[4] = {};
  float lsum = 0.f;
  const half2t onev = {(_Float16)1.0f, (_Float16)1.0f};
  _Float16* Pw = &Psm[w * 16 * 64];

  for (int kt = 0; kt < S / 64; ++kt) {
    // async stage K tile (rows=key, flat source) and V tile (rows=d)
#pragma unroll
    for (int i = 0; i < 2; ++i) {
      int chunk = i * 256 + tid;  // 512 chunks = 64 rows x 8
      int r = chunk >> 3;
      int c = (chunk & 7) ^ (r & 7);
      load_lds16(Kf + ((size_t)b * S + kt * 64 + r) * DM + h * DK + c * 8, Ksm + chunk * 8);
      load_lds16(Vb + (size_t)r * S + kt * 64 + c * 8, Vsm + chunk * 8);
    }
    // mask tile for this wave: 2 x 16B per lane, contiguous 2KB per wave
    union { halfx8 v; half2t h2[4]; } m0, m1;
    m0.v = *(const halfx8*)(Mw + (size_t)kt * 131072);
    m1.v = *(const halfx8*)(Mw + (size_t)kt * 131072 + 8);
    __syncthreads();

    // S^T = K Q^T : D row = key (quad*4+r), col = query (lane&15)
    floatx4 Sacc[4] = {};
#pragma unroll
    for (int ks = 0; ks < 2; ++ks)
#pragma unroll
      for (int nt = 0; nt < 4; ++nt) {
        halfx8 kf = *(const halfx8*)&Ksm[(nt * 16 + lo) * 64 + (((ks * 4 + quad) ^ lo7) * 8)];
        Sacc[nt] = __builtin_amdgcn_mfma_f32_16x16x32_f16(kf, qf[ks], Sacc[nt], 0, 0, 0);
      }

    // exp2 + mask multiply + packed row-sum + swizzled P store
    half2t mm[8];
    mm[0] = m0.h2[0]; mm[1] = m0.h2[1]; mm[2] = m0.h2[2]; mm[3] = m0.h2[3];
    mm[4] = m1.h2[0]; mm[5] = m1.h2[1]; mm[6] = m1.h2[2]; mm[7] = m1.h2[3];
#pragma unroll
    for (int nt = 0; nt < 4; ++nt) {
      half2t p01 = pack2(__builtin_exp2f(Sacc[nt][0]), __builtin_exp2f(Sacc[nt][1]));
      half2t p23 = pack2(__builtin_exp2f(Sacc[nt][2]), __builtin_exp2f(Sacc[nt][3]));
      p01 *= mm[nt * 2];
      p23 *= mm[nt * 2 + 1];
#ifdef HAVE_FDOT2
      lsum = __builtin_amdgcn_fdot2(__builtin_bit_cast(fp16x2, p01),
                                    __builtin_bit_cast(fp16x2, onev), lsum, false);
      lsum = __builtin_amdgcn_fdot2(__builtin_bit_cast(fp16x2, p23),
                                    __builtin_bit_cast(fp16x2, onev), lsum, false);
#else
      lsum += (float)p01[0] + (float)p01[1] + (float)p23[0] + (float)p23[1];
#endif
      union { halfx4 v; half2t h[2]; } u;
      u.h[0] = p01; u.h[1] = p23;
      // logical col nt*16+quad*4 -> chunk 2nt+(quad>>1), swizzle by row (lo)
      *(halfx4*)&Pw[lo * 64 + (((2 * nt + (quad >> 1)) ^ lo7) * 8) + (quad & 1) * 4] = u.v;
    }

    // O += P V : A = P[q][key] (row lo), B = V^T[d][key]; same-wave LDS
#pragma unroll
    for (int ks = 0; ks < 2; ++ks) {
      halfx8 pf = *(const halfx8*)&Pw[lo * 64 + (((ks * 4 + quad) ^ lo7) * 8)];
#pragma unroll
      for (int nt = 0; nt < 4; ++nt) {
        halfx8 vf = *(const halfx8*)&Vsm[(nt * 16 + lo) * 64 + (((ks * 4 + quad) ^ lo7) * 8)];
        Oacc[nt] = __builtin_amdgcn_mfma_f32_16x16x32_f16(pf, vf, Oacc[nt], 0, 0, 0);
      }
    }
    __syncthreads();
  }

  // reduce per-lane partial row-sums across the 4 quads (same query = same lo)
  lsum += __shfl_xor(lsum, 16);
  lsum += __shfl_xor(lsum, 32);

#pragma unroll
  for (int r = 0; r < 4; ++r) {
    float lr = __shfl(lsum, quad * 4 + r);  // lane (quad*4+r) holds query qb+quad*4+r
    float inv = __builtin_amdgcn_rcpf(lr);
    int q = qb + quad * 4 + r;
#pragma unroll
    for (int nt = 0; nt < 4; ++nt) {
      int d = nt * 16 + lo;
      concat[((size_t)b * S + q) * DM + h * DK + d] = (_Float16)(Oacc[nt][r] * inv);
    }
  }
}

// ---------------- output GEMM: out[4096x1024] = concat * wto^T + bias (fp32 out)
__global__ __launch_bounds__(256) void out_gemm(const _Float16* __restrict__ A,
                                                const _Float16* __restrict__ Bt,
                                                float* __restrict__ Cp,
                                                const float* __restrict__ bias) {
  __shared__ __align__(16) _Float16 Asm[128 * 64];
  __shared__ __align__(16) _Float16 Bsm[64 * 64];
  const int tid = threadIdx.x;
  const int w = tid >> 6, l = tid & 63, lo = l & 15, quad = l >> 4;
  const int lo7 = l & 7;
  const int wm = (w >> 1) * 64, wn = (w & 1) * 32;
  const int bm = blockIdx.y * 128, bn = blockIdx.x * 64;

  floatx4 acc[4][2] = {};

  for (int k0 = 0; k0 < DM; k0 += 64) {
#pragma unroll
    for (int i = 0; i < 4; ++i) {
      int chunk = i * 256 + tid;
      int r = chunk >> 3;
      int c = (chunk & 7) ^ (r & 7);
      load_lds16(A + (size_t)(bm + r) * DM + k0 + c * 8, Asm + chunk * 8);
    }
#pragma unroll
    for (int i = 0; i < 2; ++i) {
      int chunk = i * 256 + tid;
      int r = chunk >> 3;
      int c = (chunk & 7) ^ (r & 7);
      load_lds16(Bt + (size_t)(bn + r) * DM + k0 + c * 8, Bsm + chunk * 8);
    }
    __syncthreads();

#pragma unroll
    for (int ks = 0; ks < 2; ++ks) {
      halfx8 af[4], bfr[2];
#pragma unroll
      for (int mt = 0; mt < 4; ++mt)
        af[mt] = *(const halfx8*)&Asm[(wm + mt * 16 + lo) * 64 + (((ks * 4 + quad) ^ lo7) * 8)];
#pragma unroll
      for (int nt = 0; nt < 2; ++nt)
        bfr[nt] = *(const halfx8*)&Bsm[(wn + nt * 16 + lo) * 64 + (((ks * 4 + quad) ^ lo7) * 8)];
#pragma unroll
      for (int mt = 0; mt < 4; ++mt)
#pragma unroll
        for (int nt = 0; nt < 2; ++nt)
          acc[mt][nt] =
              __builtin_amdgcn_mfma_f32_16x16x32_f16(af[mt], bfr[nt], acc[mt][nt], 0, 0, 0);
    }
    __syncthreads();
  }

#pragma unroll
  for (int mt = 0; mt < 4; ++mt)
#pragma unroll
    for (int nt = 0; nt < 2; ++nt)
#pragma unroll
      for (int r = 0; r < 4; ++r) {
        int row = bm + wm + mt * 16 + quad * 4 + r;
        int col = bn + wn + nt * 16 + lo;
        Cp[(size_t)row * DM + col] = acc[mt][nt][r] + bias[col];
      }
}

extern "C" void kernel_launch(void* const* d_in, const int* in_sizes, int n_in,
                              void* d_out, int out_size, void* d_ws, size_t ws_size,
                              hipStream_t stream) {
  const float* in_q = (const float*)d_in[0];
  const float* in_k = (const float*)d_in[1];
  const float* in_v = (const float*)d_in[2];
  const int* mask = (const int*)d_in[3];
  const float* w_q = (const float*)d_in[4];
  const float* w_k = (const float*)d_in[5];
  const float* w_v = (const float*)d_in[6];
  const float* w_o = (const float*)d_in[7];
  const float* b_o = (const float*)d_in[8];
  float* out = (float*)d_out;

  char* ws = (char*)d_ws;
  constexpr size_t WB = (size_t)DM * DM * sizeof(_Float16);    // 2 MiB per weight
  constexpr size_t MB_ = (size_t)S * S * sizeof(_Float16);     // 8 MiB swizzled mask
  constexpr size_t TB = (size_t)MROWS * DM * sizeof(_Float16); // 8 MiB per tensor
  _Float16* wqkv = (_Float16*)(ws);                   // 6 MiB: wtq|wtk|wtv
  _Float16* wto = (_Float16*)(ws + 3 * WB);           // 2 MiB
  _Float16* Mt = (_Float16*)(ws + 4 * WB);            // 8 MiB
  char* p = ws + 4 * WB + MB_;
  _Float16* Qf = (_Float16*)(p);
  _Float16* Kf = (_Float16*)(p + TB);
  _Float16* Vt = (_Float16*)(p + 2 * TB);
  _Float16* xq = (_Float16*)(p + 3 * TB);
  _Float16* xk = (_Float16*)(p + 4 * TB);
  _Float16* xv = (_Float16*)(p + 5 * TB);
  _Float16* concat = xq;  // xq dead after qkv_gemm; attn writes concat there
  // total ws use: 16 MiB + 6*8 MiB = 64 MiB

  convert_w4<<<dim3(32, 32, 4), dim3(32, 8), 0, stream>>>(
      w_q, w_k, w_v, w_o, wqkv, wqkv + DM * DM, wqkv + 2 * DM * DM, wto);
  convert_in3<<<dim3(MROWS * DM / 8 / 256, 1, 3), 256, 0, stream>>>(in_q, in_k, in_v,
                                                                    xq, xk, xv);
  mask_swz<<<dim3(S * S / 8 / 256), 256, 0, stream>>>(mask, Mt);

  qkv_gemm<<<dim3(24, 32), 256, 0, stream>>>(xq, xk, xv, wqkv, Qf, Kf, Vt);
  attn_kernel<<<dim3(S / 64, NH, BATCH), 256, 0, stream>>>(Qf, Kf, Vt, Mt, concat);
  out_gemm<<<dim3(DM / 64, MROWS / 128), 256, 0, stream>>>(concat, wto, out, b_o);
}

// Round 6
// 250.693 us; speedup vs baseline: 1.1716x; 1.0621x over previous
//
#include <hip/hip_runtime.h>
#include <hip/hip_bf16.h>

typedef _Float16 halfx8 __attribute__((ext_vector_type(8)));
typedef _Float16 halfx4 __attribute__((ext_vector_type(4)));
typedef _Float16 half2t __attribute__((ext_vector_type(2)));
typedef __fp16 fp16x2 __attribute__((ext_vector_type(2)));
typedef float floatx4 __attribute__((ext_vector_type(4)));

constexpr int S = 2048;
constexpr int DM = 1024;
constexpr int NH = 16;
constexpr int DK = 64;
constexpr int BATCH = 2;
constexpr int MROWS = 4096;
// exp(x) = exp2(x * log2e); fold log2e and 1/sqrt(d_k)=1/8 into Q prescale
constexpr float QSCALE = 0.125f * 1.44269504088896340736f;

#if defined(__has_builtin)
#if __has_builtin(__builtin_amdgcn_fdot2)
#define HAVE_FDOT2 1
#endif
#if __has_builtin(__builtin_amdgcn_exp2f)
#define EXP2F(x) __builtin_amdgcn_exp2f(x)
#endif
#endif
#ifndef EXP2F
#define EXP2F(x) __builtin_exp2f(x)
#endif

static __device__ inline half2t pack2(float a, float b) {
  return __builtin_bit_cast(half2t, __builtin_amdgcn_cvt_pkrtz(a, b));
}

static __device__ inline float hdot2(half2t a, half2t b, float c) {
#ifdef HAVE_FDOT2
  return __builtin_amdgcn_fdot2(__builtin_bit_cast(fp16x2, a),
                                __builtin_bit_cast(fp16x2, b), c, false);
#else
  return c + (float)a[0] * (float)b[0] + (float)a[1] * (float)b[1];
#endif
}

// async 16B global -> LDS (wave-uniform base + lane*16; lane order = chunk order)
static __device__ inline void load_lds16(const _Float16* g, _Float16* l) {
  __builtin_amdgcn_global_load_lds((const __attribute__((address_space(1))) void*)g,
                                   (__attribute__((address_space(3))) void*)l, 16, 0, 0);
}

// ---------------- weight transpose + fp16 convert: wt[n][k] = (half)w[k][n]
__global__ void convert_w4(const float* __restrict__ w0, const float* __restrict__ w1,
                           const float* __restrict__ w2, const float* __restrict__ w3,
                           _Float16* __restrict__ o0, _Float16* __restrict__ o1,
                           _Float16* __restrict__ o2, _Float16* __restrict__ o3) {
  const float* w = (blockIdx.z == 0) ? w0 : (blockIdx.z == 1) ? w1 : (blockIdx.z == 2) ? w2 : w3;
  _Float16* wt = (blockIdx.z == 0) ? o0 : (blockIdx.z == 1) ? o1 : (blockIdx.z == 2) ? o2 : o3;
  __shared__ float tile[32][33];
  int n0 = blockIdx.x * 32, k0 = blockIdx.y * 32;
  int tx = threadIdx.x, ty = threadIdx.y;  // 32 x 8
#pragma unroll
  for (int i = 0; i < 4; ++i)
    tile[ty + i * 8][tx] = w[(k0 + ty + i * 8) * DM + n0 + tx];
  __syncthreads();
#pragma unroll
  for (int i = 0; i < 4; ++i)
    wt[(n0 + ty + i * 8) * DM + k0 + tx] = (_Float16)tile[tx][ty + i * 8];
}

// ---------------- fp32 -> fp16 elementwise, fused over 3 inputs
__global__ void convert_in3(const float* __restrict__ a0, const float* __restrict__ a1,
                            const float* __restrict__ a2, _Float16* __restrict__ o0,
                            _Float16* __restrict__ o1, _Float16* __restrict__ o2) {
  const float* a = (blockIdx.z == 0) ? a0 : (blockIdx.z == 1) ? a1 : a2;
  _Float16* o = (blockIdx.z == 0) ? o0 : (blockIdx.z == 1) ? o1 : o2;
  size_t i = ((size_t)blockIdx.x * 256 + threadIdx.x) * 8;
  float4 va = *(const float4*)(a + i);
  float4 vb = *(const float4*)(a + i + 4);
  union { halfx8 v; _Float16 h[8]; } u;
  u.h[0] = (_Float16)va.x; u.h[1] = (_Float16)va.y;
  u.h[2] = (_Float16)va.z; u.h[3] = (_Float16)va.w;
  u.h[4] = (_Float16)vb.x; u.h[5] = (_Float16)vb.y;
  u.h[6] = (_Float16)vb.z; u.h[7] = (_Float16)vb.w;
  *(halfx8*)(o + i) = u.v;
}

// ---------------- mask -> swizzled fp16 tiles Mt[kt][q][quad][16]
__global__ void mask_swz(const int* __restrict__ m, _Float16* __restrict__ Mt) {
  int t = blockIdx.x * 256 + threadIdx.x;
  int j0 = (t & 1) * 8;
  int quad = (t >> 1) & 3;
  int q = (t >> 3) & (S - 1);
  int kt = t >> 14;
  const int* src = m + (size_t)q * S + kt * 64 + (j0 >> 2) * 16 + quad * 4;
  int4 a = *(const int4*)src;
  int4 b = *(const int4*)(src + 16);
  union { halfx8 v; _Float16 h[8]; } u;
  u.h[0] = (_Float16)(a.x != 0); u.h[1] = (_Float16)(a.y != 0);
  u.h[2] = (_Float16)(a.z != 0); u.h[3] = (_Float16)(a.w != 0);
  u.h[4] = (_Float16)(b.x != 0); u.h[5] = (_Float16)(b.y != 0);
  u.h[6] = (_Float16)(b.z != 0); u.h[7] = (_Float16)(b.w != 0);
  *(halfx8*)(Mt + (size_t)t * 8) = u.v;
}

// ---------------- fused QKV GEMM (unchanged from r5): 128x128 tile, async staging
__global__ __launch_bounds__(256) void qkv_gemm(const _Float16* __restrict__ xq,
                                                const _Float16* __restrict__ xk,
                                                const _Float16* __restrict__ xv,
                                                const _Float16* __restrict__ wqkv,
                                                _Float16* __restrict__ Qf,
                                                _Float16* __restrict__ Kf,
                                                _Float16* __restrict__ Vt) {
  __shared__ __align__(16) _Float16 smem[17408];
  _Float16* Asm = smem;
  _Float16* Bsm = smem + 128 * 64;
  const int tid = threadIdx.x;
  const int w = tid >> 6, l = tid & 63, lo = l & 15, quad = l >> 4;
  const int lo7 = l & 7;
  const int wm = (w >> 1) * 64, wn = (w & 1) * 64;
  const int bx = blockIdx.x, bm = blockIdx.y * 128;
  const int wid = bx >> 3;
  const _Float16* A = (wid == 0) ? xq : (wid == 1) ? xk : xv;
  const _Float16* Bt = wqkv + (size_t)bx * 128 * DM;

  floatx4 acc[4][4] = {};

  for (int k0 = 0; k0 < DM; k0 += 64) {
#pragma unroll
    for (int i = 0; i < 4; ++i) {
      int chunk = i * 256 + tid;
      int r = chunk >> 3;
      int c = (chunk & 7) ^ (r & 7);
      load_lds16(A + (size_t)(bm + r) * DM + k0 + c * 8, Asm + chunk * 8);
    }
#pragma unroll
    for (int i = 0; i < 4; ++i) {
      int chunk = i * 256 + tid;
      int r = chunk >> 3;
      int c = (chunk & 7) ^ (r & 7);
      load_lds16(Bt + (size_t)r * DM + k0 + c * 8, Bsm + chunk * 8);
    }
    __syncthreads();

#pragma unroll
    for (int ks = 0; ks < 2; ++ks) {
      halfx8 af[4], bf[4];
#pragma unroll
      for (int mt = 0; mt < 4; ++mt)
        af[mt] = *(const halfx8*)&Asm[(wm + mt * 16 + lo) * 64 + (((ks * 4 + quad) ^ lo7) * 8)];
#pragma unroll
      for (int nt = 0; nt < 4; ++nt)
        bf[nt] = *(const halfx8*)&Bsm[(wn + nt * 16 + lo) * 64 + (((ks * 4 + quad) ^ lo7) * 8)];
#pragma unroll
      for (int mt = 0; mt < 4; ++mt)
#pragma unroll
        for (int nt = 0; nt < 4; ++nt)
          acc[mt][nt] =
              __builtin_amdgcn_mfma_f32_16x16x32_f16(af[mt], bf[nt], acc[mt][nt], 0, 0, 0);
    }
    __syncthreads();
  }

  if (wid == 2) {
    constexpr int LDTT = 136;
    _Float16* tb = smem;
#pragma unroll
    for (int mt = 0; mt < 4; ++mt)
#pragma unroll
      for (int nt = 0; nt < 4; ++nt)
#pragma unroll
        for (int r = 0; r < 4; ++r) {
          int dl = wn + nt * 16 + lo;
          int sl = wm + mt * 16 + quad * 4 + r;
          tb[dl * LDTT + sl] = (_Float16)acc[mt][nt][r];
        }
    __syncthreads();
    const int b = bm >> 11, s0 = bm & (S - 1);
    const int d2 = tid >> 1, chunk = (tid & 1) * 64;
    const int dg = ((bx & 7) * 128 + d2);
    const int h = dg >> 6, dd = dg & 63;
    _Float16* O = Vt + ((size_t)(b * NH + h) * DK + dd) * S + s0 + chunk;
#pragma unroll
    for (int j = 0; j < 8; ++j)
      *(halfx8*)(O + j * 8) = *(const halfx8*)&tb[d2 * LDTT + chunk + j * 8];
    return;
  }

  _Float16* Out = (wid == 0) ? Qf : Kf;
  const float scale = (wid == 0) ? QSCALE : 1.0f;
#pragma unroll
  for (int mt = 0; mt < 4; ++mt)
#pragma unroll
    for (int nt = 0; nt < 4; ++nt)
#pragma unroll
      for (int r = 0; r < 4; ++r) {
        int row = bm + wm + mt * 16 + quad * 4 + r;
        int col = (bx & 7) * 128 + wn + nt * 16 + lo;
        Out[(size_t)row * DM + col] = (_Float16)(acc[mt][nt][r] * scale);
      }
}

// ---------------- flash attention v3: 32q/wave (2 groups sharing K/V frags),
// double-buffered prefetch-after-barrier staging, raw v_exp_f32.
__global__ __launch_bounds__(256, 2) void attn_kernel(const _Float16* __restrict__ Qf,
                                                      const _Float16* __restrict__ Kf,
                                                      const _Float16* __restrict__ Vt,
                                                      const _Float16* __restrict__ Mt,
                                                      _Float16* __restrict__ concat) {
  __shared__ __align__(16) _Float16 K0s[64 * 64], K1s[64 * 64];
  __shared__ __align__(16) _Float16 V0s[64 * 64], V1s[64 * 64];
  __shared__ __align__(16) _Float16 Psm[4 * 32 * 64];

  const int tid = threadIdx.x;
  const int w = tid >> 6, l = tid & 63, lo = l & 15, quad = l >> 4, lo7 = l & 7;
  const int qb = blockIdx.x * 128 + w * 32;  // wave's 32 q-rows (2 groups of 16)
  const int h = blockIdx.y, b = blockIdx.z;

  const _Float16* Kbase = Kf + (size_t)b * S * DM + h * DK;
  const _Float16* Vb = Vt + (size_t)(b * NH + h) * DK * S;
  _Float16* Pw = Psm + w * 32 * 64;

  const int r0 = tid >> 3, c0 = (tid & 7) ^ (r0 & 7);
  const int r1 = (256 + tid) >> 3, c1 = ((256 + tid) & 7) ^ (r1 & 7);

  halfx8 qf[2][2];
  const _Float16* Mp[2];
#pragma unroll
  for (int g = 0; g < 2; ++g) {
#pragma unroll
    for (int ks = 0; ks < 2; ++ks)
      qf[g][ks] = *(const halfx8*)(Qf + ((size_t)b * S + qb + g * 16 + lo) * DM + h * DK +
                                   ks * 32 + quad * 8);
    Mp[g] = Mt + ((size_t)(qb + g * 16 + lo) * 4 + quad) * 16;
  }

  floatx4 Oacc[2][4] = {};
  float lsum[2] = {0.f, 0.f};
  const half2t onev = {(_Float16)1.0f, (_Float16)1.0f};

  auto stage = [&](int kt, _Float16* Kd, _Float16* Vd) {
    load_lds16(Kbase + (size_t)(kt * 64 + r0) * DM + c0 * 8, Kd + tid * 8);
    load_lds16(Vb + (size_t)r0 * S + kt * 64 + c0 * 8, Vd + tid * 8);
    load_lds16(Kbase + (size_t)(kt * 64 + r1) * DM + c1 * 8, Kd + (256 + tid) * 8);
    load_lds16(Vb + (size_t)r1 * S + kt * 64 + c1 * 8, Vd + (256 + tid) * 8);
  };

  auto tile = [&](const _Float16* Kc, const _Float16* Vc, const halfx8* mc) {
    floatx4 Sacc[2][4] = {};
    // S^T = K Q^T for both q-groups, K-frags shared
#pragma unroll
    for (int ks = 0; ks < 2; ++ks)
#pragma unroll
      for (int nt = 0; nt < 4; ++nt) {
        halfx8 kf = *(const halfx8*)&Kc[(nt * 16 + lo) * 64 + (((ks * 4 + quad) ^ lo7) * 8)];
        Sacc[0][nt] = __builtin_amdgcn_mfma_f32_16x16x32_f16(kf, qf[0][ks], Sacc[0][nt], 0, 0, 0);
        Sacc[1][nt] = __builtin_amdgcn_mfma_f32_16x16x32_f16(kf, qf[1][ks], Sacc[1][nt], 0, 0, 0);
      }
    // exp2 + mask + row-sum + P store (per group)
#pragma unroll
    for (int g = 0; g < 2; ++g) {
      union { halfx8 v; half2t h2[4]; } mu0, mu1;
      mu0.v = mc[g * 2];
      mu1.v = mc[g * 2 + 1];
      half2t mm[8] = {mu0.h2[0], mu0.h2[1], mu0.h2[2], mu0.h2[3],
                      mu1.h2[0], mu1.h2[1], mu1.h2[2], mu1.h2[3]};
#pragma unroll
      for (int nt = 0; nt < 4; ++nt) {
        half2t p01 = pack2(EXP2F(Sacc[g][nt][0]), EXP2F(Sacc[g][nt][1]));
        half2t p23 = pack2(EXP2F(Sacc[g][nt][2]), EXP2F(Sacc[g][nt][3]));
        p01 *= mm[nt * 2];
        p23 *= mm[nt * 2 + 1];
        lsum[g] = hdot2(p01, onev, lsum[g]);
        lsum[g] = hdot2(p23, onev, lsum[g]);
        union { halfx4 v; half2t hh[2]; } u;
        u.hh[0] = p01;
        u.hh[1] = p23;
        *(halfx4*)&Pw[(g * 16 + lo) * 64 + (((2 * nt + (quad >> 1)) ^ lo7) * 8) +
                      (quad & 1) * 4] = u.v;
      }
    }
    // O += P V, V-frags shared across groups
#pragma unroll
    for (int ks = 0; ks < 2; ++ks) {
      halfx8 pf0 = *(const halfx8*)&Pw[lo * 64 + (((ks * 4 + quad) ^ lo7) * 8)];
      halfx8 pf1 = *(const halfx8*)&Pw[(16 + lo) * 64 + (((ks * 4 + quad) ^ lo7) * 8)];
#pragma unroll
      for (int nt = 0; nt < 4; ++nt) {
        halfx8 vf = *(const halfx8*)&Vc[(nt * 16 + lo) * 64 + (((ks * 4 + quad) ^ lo7) * 8)];
        Oacc[0][nt] = __builtin_amdgcn_mfma_f32_16x16x32_f16(pf0, vf, Oacc[0][nt], 0, 0, 0);
        Oacc[1][nt] = __builtin_amdgcn_mfma_f32_16x16x32_f16(pf1, vf, Oacc[1][nt], 0, 0, 0);
      }
    }
  };

  // prologue: stage tile 0, prefetch mask 0
  halfx8 mr[4];
#pragma unroll
  for (int g = 0; g < 2; ++g) {
    mr[g * 2] = *(const halfx8*)(Mp[g]);
    mr[g * 2 + 1] = *(const halfx8*)(Mp[g] + 8);
  }
  stage(0, K0s, V0s);

  for (int kt = 0; kt < S / 64; kt += 2) {
    __syncthreads();                 // drains DMA(kt) -> buf0; all reads of buf1 done
    stage(kt + 1, K1s, V1s);         // prefetch next tile (hidden under compute)
    halfx8 mc[4] = {mr[0], mr[1], mr[2], mr[3]};
#pragma unroll
    for (int g = 0; g < 2; ++g) {    // prefetch next mask
      mr[g * 2] = *(const halfx8*)(Mp[g] + (size_t)(kt + 1) * 131072);
      mr[g * 2 + 1] = *(const halfx8*)(Mp[g] + (size_t)(kt + 1) * 131072 + 8);
    }
    tile(K0s, V0s, mc);
    __syncthreads();                 // drains DMA(kt+1) -> buf1; reads of buf0 done
    if (kt + 2 < S / 64) stage(kt + 2, K0s, V0s);
    mc[0] = mr[0]; mc[1] = mr[1]; mc[2] = mr[2]; mc[3] = mr[3];
    if (kt + 2 < S / 64) {
#pragma unroll
      for (int g = 0; g < 2; ++g) {
        mr[g * 2] = *(const halfx8*)(Mp[g] + (size_t)(kt + 2) * 131072);
        mr[g * 2 + 1] = *(const halfx8*)(Mp[g] + (size_t)(kt + 2) * 131072 + 8);
      }
    }
    tile(K1s, V1s, mc);
  }

  // reduce per-lane partial row-sums across the 4 quads
#pragma unroll
  for (int g = 0; g < 2; ++g) {
    lsum[g] += __shfl_xor(lsum[g], 16);
    lsum[g] += __shfl_xor(lsum[g], 32);
  }

#pragma unroll
  for (int g = 0; g < 2; ++g)
#pragma unroll
    for (int r = 0; r < 4; ++r) {
      float lr = __shfl(lsum[g], quad * 4 + r);
      float inv = __builtin_amdgcn_rcpf(lr);
      int q = qb + g * 16 + quad * 4 + r;
#pragma unroll
      for (int nt = 0; nt < 4; ++nt) {
        int d = nt * 16 + lo;
        concat[((size_t)b * S + q) * DM + h * DK + d] = (_Float16)(Oacc[g][nt][r] * inv);
      }
    }
}

// ---------------- output GEMM: 128x128 tile, dbuf prefetch staging, fp32 out + bias
__global__ __launch_bounds__(256) void out_gemm(const _Float16* __restrict__ A,
                                                const _Float16* __restrict__ Bt,
                                                float* __restrict__ Cp,
                                                const float* __restrict__ bias) {
  __shared__ __align__(16) _Float16 A0s[128 * 64], A1s[128 * 64];
  __shared__ __align__(16) _Float16 B0s[128 * 64], B1s[128 * 64];
  const int tid = threadIdx.x;
  const int w = tid >> 6, l = tid & 63, lo = l & 15, quad = l >> 4, lo7 = l & 7;
  const int wm = (w >> 1) * 64, wn = (w & 1) * 64;
  const int bm = blockIdx.y * 128, bn = blockIdx.x * 128;

  floatx4 acc[4][4] = {};

  auto stageg = [&](int k0, _Float16* Ad, _Float16* Bd) {
#pragma unroll
    for (int i = 0; i < 4; ++i) {
      int chunk = i * 256 + tid;
      int rr = chunk >> 3;
      int cc = (chunk & 7) ^ (rr & 7);
      load_lds16(A + (size_t)(bm + rr) * DM + k0 + cc * 8, Ad + chunk * 8);
      load_lds16(Bt + (size_t)(bn + rr) * DM + k0 + cc * 8, Bd + chunk * 8);
    }
  };
  auto comp = [&](const _Float16* As, const _Float16* Bs) {
#pragma unroll
    for (int ks = 0; ks < 2; ++ks) {
      halfx8 af[4], bf[4];
#pragma unroll
      for (int mt = 0; mt < 4; ++mt)
        af[mt] = *(const halfx8*)&As[(wm + mt * 16 + lo) * 64 + (((ks * 4 + quad) ^ lo7) * 8)];
#pragma unroll
      for (int nt = 0; nt < 4; ++nt)
        bf[nt] = *(const halfx8*)&Bs[(wn + nt * 16 + lo) * 64 + (((ks * 4 + quad) ^ lo7) * 8)];
#pragma unroll
      for (int mt = 0; mt < 4; ++mt)
#pragma unroll
        for (int nt = 0; nt < 4; ++nt)
          acc[mt][nt] =
              __builtin_amdgcn_mfma_f32_16x16x32_f16(af[mt], bf[nt], acc[mt][nt], 0, 0, 0);
    }
  };

  stageg(0, A0s, B0s);
  for (int k0 = 0; k0 < DM; k0 += 128) {
    __syncthreads();
    stageg(k0 + 64, A1s, B1s);  // k0+64 <= 960 always valid
    comp(A0s, B0s);
    __syncthreads();
    if (k0 + 128 < DM) stageg(k0 + 128, A0s, B0s);
    comp(A1s, B1s);
  }

  float bv[4];
#pragma unroll
  for (int nt = 0; nt < 4; ++nt) bv[nt] = bias[bn + wn + nt * 16 + lo];
#pragma unroll
  for (int mt = 0; mt < 4; ++mt)
#pragma unroll
    for (int nt = 0; nt < 4; ++nt)
#pragma unroll
      for (int r = 0; r < 4; ++r) {
        int row = bm + wm + mt * 16 + quad * 4 + r;
        int col = bn + wn + nt * 16 + lo;
        Cp[(size_t)row * DM + col] = acc[mt][nt][r] + bv[nt];
      }
}

extern "C" void kernel_launch(void* const* d_in, const int* in_sizes, int n_in,
                              void* d_out, int out_size, void* d_ws, size_t ws_size,
                              hipStream_t stream) {
  const float* in_q = (const float*)d_in[0];
  const float* in_k = (const float*)d_in[1];
  const float* in_v = (const float*)d_in[2];
  const int* mask = (const int*)d_in[3];
  const float* w_q = (const float*)d_in[4];
  const float* w_k = (const float*)d_in[5];
  const float* w_v = (const float*)d_in[6];
  const float* w_o = (const float*)d_in[7];
  const float* b_o = (const float*)d_in[8];
  float* out = (float*)d_out;

  char* ws = (char*)d_ws;
  constexpr size_t WB = (size_t)DM * DM * sizeof(_Float16);
  constexpr size_t MB_ = (size_t)S * S * sizeof(_Float16);
  constexpr size_t TB = (size_t)MROWS * DM * sizeof(_Float16);
  _Float16* wqkv = (_Float16*)(ws);
  _Float16* wto = (_Float16*)(ws + 3 * WB);
  _Float16* Mt = (_Float16*)(ws + 4 * WB);
  char* p = ws + 4 * WB + MB_;
  _Float16* Qf = (_Float16*)(p);
  _Float16* Kf = (_Float16*)(p + TB);
  _Float16* Vt = (_Float16*)(p + 2 * TB);
  _Float16* xq = (_Float16*)(p + 3 * TB);
  _Float16* xk = (_Float16*)(p + 4 * TB);
  _Float16* xv = (_Float16*)(p + 5 * TB);
  _Float16* concat = xq;  // xq dead after qkv_gemm

  convert_w4<<<dim3(32, 32, 4), dim3(32, 8), 0, stream>>>(
      w_q, w_k, w_v, w_o, wqkv, wqkv + DM * DM, wqkv + 2 * DM * DM, wto);
  convert_in3<<<dim3(MROWS * DM / 8 / 256, 1, 3), 256, 0, stream>>>(in_q, in_k, in_v,
                                                                    xq, xk, xv);
  mask_swz<<<dim3(S * S / 8 / 256), 256, 0, stream>>>(mask, Mt);

  qkv_gemm<<<dim3(24, 32), 256, 0, stream>>>(xq, xk, xv, wqkv, Qf, Kf, Vt);
  attn_kernel<<<dim3(S / 128, NH, BATCH), 256, 0, stream>>>(Qf, Kf, Vt, Mt, concat);
  out_gemm<<<dim3(DM / 128, MROWS / 128), 256, 0, stream>>>(concat, wto, out, b_o);
}

// Round 7
// 245.696 us; speedup vs baseline: 1.1954x; 1.0203x over previous
//
#include <hip/hip_runtime.h>
#include <hip/hip_bf16.h>

typedef _Float16 halfx8 __attribute__((ext_vector_type(8)));
typedef _Float16 halfx4 __attribute__((ext_vector_type(4)));
typedef _Float16 half2t __attribute__((ext_vector_type(2)));
typedef __fp16 fp16x2 __attribute__((ext_vector_type(2)));
typedef float floatx4 __attribute__((ext_vector_type(4)));

constexpr int S = 2048;
constexpr int DM = 1024;
constexpr int NH = 16;
constexpr int DK = 64;
constexpr int BATCH = 2;
constexpr int MROWS = 4096;
// exp(x) = exp2(x * log2e); fold log2e and 1/sqrt(d_k)=1/8 into Q prescale
constexpr float QSCALE = 0.125f * 1.44269504088896340736f;

#if defined(__has_builtin)
#if __has_builtin(__builtin_amdgcn_fdot2)
#define HAVE_FDOT2 1
#endif
#if __has_builtin(__builtin_amdgcn_exp2f)
#define EXP2F(x) __builtin_amdgcn_exp2f(x)
#endif
#endif
#ifndef EXP2F
#define EXP2F(x) __builtin_exp2f(x)
#endif

static __device__ inline half2t pack2(float a, float b) {
  return __builtin_bit_cast(half2t, __builtin_amdgcn_cvt_pkrtz(a, b));
}

static __device__ inline float hdot2(half2t a, half2t b, float c) {
#ifdef HAVE_FDOT2
  return __builtin_amdgcn_fdot2(__builtin_bit_cast(fp16x2, a),
                                __builtin_bit_cast(fp16x2, b), c, false);
#else
  return c + (float)a[0] * (float)b[0] + (float)a[1] * (float)b[1];
#endif
}

// async 16B global -> LDS (wave-uniform base + lane*16; lane order = chunk order)
static __device__ inline void load_lds16(const _Float16* g, _Float16* l) {
  __builtin_amdgcn_global_load_lds((const __attribute__((address_space(1))) void*)g,
                                   (__attribute__((address_space(3))) void*)l, 16, 0, 0);
}

// ---------------- unified prep: weight transpose+cvt | input cvt | mask swizzle
// blocks [0,4096): weights; [4096,10240): inputs; [10240,12288): mask
__global__ __launch_bounds__(256) void prep(const float* __restrict__ w_q,
                                            const float* __restrict__ w_k,
                                            const float* __restrict__ w_v,
                                            const float* __restrict__ w_o,
                                            _Float16* __restrict__ wqkv,
                                            _Float16* __restrict__ wto,
                                            const float* __restrict__ in_q,
                                            const float* __restrict__ in_k,
                                            const float* __restrict__ in_v,
                                            _Float16* __restrict__ xq,
                                            _Float16* __restrict__ xk,
                                            _Float16* __restrict__ xv,
                                            const int* __restrict__ mask,
                                            _Float16* __restrict__ Mt) {
  __shared__ float tile[32][33];
  const int bid = blockIdx.x;
  const int tid = threadIdx.x;
  if (bid < 4096) {
    // weight transpose + fp16 convert: wt[n][k] = (half)w[k][n]
    int wsel = bid >> 10, t = bid & 1023;
    const float* w = (wsel == 0) ? w_q : (wsel == 1) ? w_k : (wsel == 2) ? w_v : w_o;
    _Float16* wt = (wsel < 3) ? (wqkv + (size_t)wsel * DM * DM) : wto;
    int n0 = (t & 31) * 32, k0 = (t >> 5) * 32;
    int tx = tid & 31, ty = tid >> 5;  // 32 x 8
#pragma unroll
    for (int i = 0; i < 4; ++i)
      tile[ty + i * 8][tx] = w[(size_t)(k0 + ty + i * 8) * DM + n0 + tx];
    __syncthreads();
#pragma unroll
    for (int i = 0; i < 4; ++i)
      wt[(size_t)(n0 + ty + i * 8) * DM + k0 + tx] = (_Float16)tile[tx][ty + i * 8];
  } else if (bid < 10240) {
    // fp32 -> fp16 elementwise
    int idx = bid - 4096, isel = idx >> 11, blk = idx & 2047;
    const float* a = (isel == 0) ? in_q : (isel == 1) ? in_k : in_v;
    _Float16* o = (isel == 0) ? xq : (isel == 1) ? xk : xv;
    size_t i = ((size_t)blk * 256 + tid) * 8;
    float4 va = *(const float4*)(a + i);
    float4 vb = *(const float4*)(a + i + 4);
    union { halfx8 v; _Float16 h[8]; } u;
    u.h[0] = (_Float16)va.x; u.h[1] = (_Float16)va.y;
    u.h[2] = (_Float16)va.z; u.h[3] = (_Float16)va.w;
    u.h[4] = (_Float16)vb.x; u.h[5] = (_Float16)vb.y;
    u.h[6] = (_Float16)vb.z; u.h[7] = (_Float16)vb.w;
    *(halfx8*)(o + i) = u.v;
  } else {
    // mask -> swizzled fp16 tiles Mt[kt][q][quad][16]
    int t = (bid - 10240) * 256 + tid;
    int j0 = (t & 1) * 8;
    int quad = (t >> 1) & 3;
    int q = (t >> 3) & (S - 1);
    int kt = t >> 14;
    const int* src = mask + (size_t)q * S + kt * 64 + (j0 >> 2) * 16 + quad * 4;
    int4 a = *(const int4*)src;
    int4 b = *(const int4*)(src + 16);
    union { halfx8 v; _Float16 h[8]; } u;
    u.h[0] = (_Float16)(a.x != 0); u.h[1] = (_Float16)(a.y != 0);
    u.h[2] = (_Float16)(a.z != 0); u.h[3] = (_Float16)(a.w != 0);
    u.h[4] = (_Float16)(b.x != 0); u.h[5] = (_Float16)(b.y != 0);
    u.h[6] = (_Float16)(b.z != 0); u.h[7] = (_Float16)(b.w != 0);
    *(halfx8*)(Mt + (size_t)t * 8) = u.v;
  }
}

// ---------------- fused QKV GEMM: 128x128 tile, async staging, swizzled LDS
__global__ __launch_bounds__(256) void qkv_gemm(const _Float16* __restrict__ xq,
                                                const _Float16* __restrict__ xk,
                                                const _Float16* __restrict__ xv,
                                                const _Float16* __restrict__ wqkv,
                                                _Float16* __restrict__ Qf,
                                                _Float16* __restrict__ Kf,
                                                _Float16* __restrict__ Vt) {
  __shared__ __align__(16) _Float16 smem[17408];
  _Float16* Asm = smem;
  _Float16* Bsm = smem + 128 * 64;
  const int tid = threadIdx.x;
  const int w = tid >> 6, l = tid & 63, lo = l & 15, quad = l >> 4;
  const int lo7 = l & 7;
  const int wm = (w >> 1) * 64, wn = (w & 1) * 64;
  const int bx = blockIdx.x, bm = blockIdx.y * 128;
  const int wid = bx >> 3;
  const _Float16* A = (wid == 0) ? xq : (wid == 1) ? xk : xv;
  const _Float16* Bt = wqkv + (size_t)bx * 128 * DM;

  floatx4 acc[4][4] = {};

  for (int k0 = 0; k0 < DM; k0 += 64) {
#pragma unroll
    for (int i = 0; i < 4; ++i) {
      int chunk = i * 256 + tid;
      int r = chunk >> 3;
      int c = (chunk & 7) ^ (r & 7);
      load_lds16(A + (size_t)(bm + r) * DM + k0 + c * 8, Asm + chunk * 8);
    }
#pragma unroll
    for (int i = 0; i < 4; ++i) {
      int chunk = i * 256 + tid;
      int r = chunk >> 3;
      int c = (chunk & 7) ^ (r & 7);
      load_lds16(Bt + (size_t)r * DM + k0 + c * 8, Bsm + chunk * 8);
    }
    __syncthreads();

#pragma unroll
    for (int ks = 0; ks < 2; ++ks) {
      halfx8 af[4], bf[4];
#pragma unroll
      for (int mt = 0; mt < 4; ++mt)
        af[mt] = *(const halfx8*)&Asm[(wm + mt * 16 + lo) * 64 + (((ks * 4 + quad) ^ lo7) * 8)];
#pragma unroll
      for (int nt = 0; nt < 4; ++nt)
        bf[nt] = *(const halfx8*)&Bsm[(wn + nt * 16 + lo) * 64 + (((ks * 4 + quad) ^ lo7) * 8)];
#pragma unroll
      for (int mt = 0; mt < 4; ++mt)
#pragma unroll
        for (int nt = 0; nt < 4; ++nt)
          acc[mt][nt] =
              __builtin_amdgcn_mfma_f32_16x16x32_f16(af[mt], bf[nt], acc[mt][nt], 0, 0, 0);
    }
    __syncthreads();
  }

  if (wid == 2) {
    constexpr int LDTT = 136;
    _Float16* tb = smem;
#pragma unroll
    for (int mt = 0; mt < 4; ++mt)
#pragma unroll
      for (int nt = 0; nt < 4; ++nt)
#pragma unroll
        for (int r = 0; r < 4; ++r) {
          int dl = wn + nt * 16 + lo;
          int sl = wm + mt * 16 + quad * 4 + r;
          tb[dl * LDTT + sl] = (_Float16)acc[mt][nt][r];
        }
    __syncthreads();
    const int b = bm >> 11, s0 = bm & (S - 1);
    const int d2 = tid >> 1, chunk = (tid & 1) * 64;
    const int dg = ((bx & 7) * 128 + d2);
    const int h = dg >> 6, dd = dg & 63;
    _Float16* O = Vt + ((size_t)(b * NH + h) * DK + dd) * S + s0 + chunk;
#pragma unroll
    for (int j = 0; j < 8; ++j)
      *(halfx8*)(O + j * 8) = *(const halfx8*)&tb[d2 * LDTT + chunk + j * 8];
    return;
  }

  _Float16* Out = (wid == 0) ? Qf : Kf;
  const float scale = (wid == 0) ? QSCALE : 1.0f;
#pragma unroll
  for (int mt = 0; mt < 4; ++mt)
#pragma unroll
    for (int nt = 0; nt < 4; ++nt)
#pragma unroll
      for (int r = 0; r < 4; ++r) {
        int row = bm + wm + mt * 16 + quad * 4 + r;
        int col = (bx & 7) * 128 + wn + nt * 16 + lo;
        Out[(size_t)row * DM + col] = (_Float16)(acc[mt][nt][r] * scale);
      }
}

// ---------------- flash attention v4: 2-wave blocks (64q), 4 blocks/CU,
// 32q/wave (2 groups share K/V frags), dbuf prefetch-after-barrier staging.
__global__ __launch_bounds__(128, 2) void attn_kernel(const _Float16* __restrict__ Qf,
                                                      const _Float16* __restrict__ Kf,
                                                      const _Float16* __restrict__ Vt,
                                                      const _Float16* __restrict__ Mt,
                                                      _Float16* __restrict__ concat) {
  __shared__ __align__(16) _Float16 K0s[64 * 64], K1s[64 * 64];
  __shared__ __align__(16) _Float16 V0s[64 * 64], V1s[64 * 64];
  __shared__ __align__(16) _Float16 Psm[2 * 32 * 64];
  // total LDS = 32KB (K/V dbuf) + 8KB (P) = 40KB -> 4 blocks/CU

  const int tid = threadIdx.x;
  const int w = tid >> 6, l = tid & 63, lo = l & 15, quad = l >> 4, lo7 = l & 7;
  const int qb = blockIdx.x * 64 + w * 32;  // wave's 32 q-rows (2 groups of 16)
  const int h = blockIdx.y, b = blockIdx.z;

  const _Float16* Kbase = Kf + (size_t)b * S * DM + h * DK;
  const _Float16* Vb = Vt + (size_t)(b * NH + h) * DK * S;
  _Float16* Pw = Psm + w * 32 * 64;

  halfx8 qf[2][2];
  const _Float16* Mp[2];
#pragma unroll
  for (int g = 0; g < 2; ++g) {
#pragma unroll
    for (int ks = 0; ks < 2; ++ks)
      qf[g][ks] = *(const halfx8*)(Qf + ((size_t)b * S + qb + g * 16 + lo) * DM + h * DK +
                                   ks * 32 + quad * 8);
    Mp[g] = Mt + ((size_t)(qb + g * 16 + lo) * 4 + quad) * 16;
  }

  floatx4 Oacc[2][4] = {};
  float lsum[2] = {0.f, 0.f};
  const half2t onev = {(_Float16)1.0f, (_Float16)1.0f};

  auto stage = [&](int kt, _Float16* Kd, _Float16* Vd) {
#pragma unroll
    for (int i = 0; i < 4; ++i) {
      int chunk = i * 128 + tid;  // 512 chunks = 64 rows x 8
      int r = chunk >> 3;
      int c = (chunk & 7) ^ (r & 7);
      load_lds16(Kbase + (size_t)(kt * 64 + r) * DM + c * 8, Kd + chunk * 8);
      load_lds16(Vb + (size_t)r * S + kt * 64 + c * 8, Vd + chunk * 8);
    }
  };

  auto tile = [&](const _Float16* Kc, const _Float16* Vc, const halfx8* mc) {
    floatx4 Sacc[2][4] = {};
#pragma unroll
    for (int ks = 0; ks < 2; ++ks)
#pragma unroll
      for (int nt = 0; nt < 4; ++nt) {
        halfx8 kf = *(const halfx8*)&Kc[(nt * 16 + lo) * 64 + (((ks * 4 + quad) ^ lo7) * 8)];
        Sacc[0][nt] = __builtin_amdgcn_mfma_f32_16x16x32_f16(kf, qf[0][ks], Sacc[0][nt], 0, 0, 0);
        Sacc[1][nt] = __builtin_amdgcn_mfma_f32_16x16x32_f16(kf, qf[1][ks], Sacc[1][nt], 0, 0, 0);
      }
#pragma unroll
    for (int g = 0; g < 2; ++g) {
      union { halfx8 v; half2t h2[4]; } mu0, mu1;
      mu0.v = mc[g * 2];
      mu1.v = mc[g * 2 + 1];
      half2t mm[8] = {mu0.h2[0], mu0.h2[1], mu0.h2[2], mu0.h2[3],
                      mu1.h2[0], mu1.h2[1], mu1.h2[2], mu1.h2[3]};
#pragma unroll
      for (int nt = 0; nt < 4; ++nt) {
        half2t p01 = pack2(EXP2F(Sacc[g][nt][0]), EXP2F(Sacc[g][nt][1]));
        half2t p23 = pack2(EXP2F(Sacc[g][nt][2]), EXP2F(Sacc[g][nt][3]));
        p01 *= mm[nt * 2];
        p23 *= mm[nt * 2 + 1];
        lsum[g] = hdot2(p01, onev, lsum[g]);
        lsum[g] = hdot2(p23, onev, lsum[g]);
        union { halfx4 v; half2t hh[2]; } u;
        u.hh[0] = p01;
        u.hh[1] = p23;
        *(halfx4*)&Pw[(g * 16 + lo) * 64 + (((2 * nt + (quad >> 1)) ^ lo7) * 8) +
                      (quad & 1) * 4] = u.v;
      }
    }
#pragma unroll
    for (int ks = 0; ks < 2; ++ks) {
      halfx8 pf0 = *(const halfx8*)&Pw[lo * 64 + (((ks * 4 + quad) ^ lo7) * 8)];
      halfx8 pf1 = *(const halfx8*)&Pw[(16 + lo) * 64 + (((ks * 4 + quad) ^ lo7) * 8)];
#pragma unroll
      for (int nt = 0; nt < 4; ++nt) {
        halfx8 vf = *(const halfx8*)&Vc[(nt * 16 + lo) * 64 + (((ks * 4 + quad) ^ lo7) * 8)];
        Oacc[0][nt] = __builtin_amdgcn_mfma_f32_16x16x32_f16(pf0, vf, Oacc[0][nt], 0, 0, 0);
        Oacc[1][nt] = __builtin_amdgcn_mfma_f32_16x16x32_f16(pf1, vf, Oacc[1][nt], 0, 0, 0);
      }
    }
  };

  halfx8 mr[4];
#pragma unroll
  for (int g = 0; g < 2; ++g) {
    mr[g * 2] = *(const halfx8*)(Mp[g]);
    mr[g * 2 + 1] = *(const halfx8*)(Mp[g] + 8);
  }
  stage(0, K0s, V0s);

  for (int kt = 0; kt < S / 64; kt += 2) {
    __syncthreads();                 // drains DMA(kt) -> buf0; reads of buf1 done
    stage(kt + 1, K1s, V1s);         // prefetch hidden under compute
    halfx8 mc[4] = {mr[0], mr[1], mr[2], mr[3]};
#pragma unroll
    for (int g = 0; g < 2; ++g) {
      mr[g * 2] = *(const halfx8*)(Mp[g] + (size_t)(kt + 1) * 131072);
      mr[g * 2 + 1] = *(const halfx8*)(Mp[g] + (size_t)(kt + 1) * 131072 + 8);
    }
    tile(K0s, V0s, mc);
    __syncthreads();                 // drains DMA(kt+1) -> buf1; reads of buf0 done
    if (kt + 2 < S / 64) stage(kt + 2, K0s, V0s);
    mc[0] = mr[0]; mc[1] = mr[1]; mc[2] = mr[2]; mc[3] = mr[3];
    if (kt + 2 < S / 64) {
#pragma unroll
      for (int g = 0; g < 2; ++g) {
        mr[g * 2] = *(const halfx8*)(Mp[g] + (size_t)(kt + 2) * 131072);
        mr[g * 2 + 1] = *(const halfx8*)(Mp[g] + (size_t)(kt + 2) * 131072 + 8);
      }
    }
    tile(K1s, V1s, mc);
  }

#pragma unroll
  for (int g = 0; g < 2; ++g) {
    lsum[g] += __shfl_xor(lsum[g], 16);
    lsum[g] += __shfl_xor(lsum[g], 32);
  }

#pragma unroll
  for (int g = 0; g < 2; ++g)
#pragma unroll
    for (int r = 0; r < 4; ++r) {
      float lr = __shfl(lsum[g], quad * 4 + r);
      float inv = __builtin_amdgcn_rcpf(lr);
      int q = qb + g * 16 + quad * 4 + r;
#pragma unroll
      for (int nt = 0; nt < 4; ++nt) {
        int d = nt * 16 + lo;
        concat[((size_t)b * S + q) * DM + h * DK + d] = (_Float16)(Oacc[g][nt][r] * inv);
      }
    }
}

// ---------------- output GEMM: 128x64 tile, dbuf prefetch, fp32 out + bias
__global__ __launch_bounds__(256) void out_gemm(const _Float16* __restrict__ A,
                                                const _Float16* __restrict__ Bt,
                                                float* __restrict__ Cp,
                                                const float* __restrict__ bias) {
  __shared__ __align__(16) _Float16 A0s[128 * 64], A1s[128 * 64];
  __shared__ __align__(16) _Float16 B0s[64 * 64], B1s[64 * 64];
  // LDS = 48KB -> 3 blocks/CU
  const int tid = threadIdx.x;
  const int w = tid >> 6, l = tid & 63, lo = l & 15, quad = l >> 4, lo7 = l & 7;
  const int wm = (w >> 1) * 64, wn = (w & 1) * 32;
  const int bm = blockIdx.y * 128, bn = blockIdx.x * 64;

  floatx4 acc[4][2] = {};

  auto stageg = [&](int k0, _Float16* Ad, _Float16* Bd) {
#pragma unroll
    for (int i = 0; i < 4; ++i) {
      int chunk = i * 256 + tid;
      int rr = chunk >> 3;
      int cc = (chunk & 7) ^ (rr & 7);
      load_lds16(A + (size_t)(bm + rr) * DM + k0 + cc * 8, Ad + chunk * 8);
    }
#pragma unroll
    for (int i = 0; i < 2; ++i) {
      int chunk = i * 256 + tid;
      int rr = chunk >> 3;
      int cc = (chunk & 7) ^ (rr & 7);
      load_lds16(Bt + (size_t)(bn + rr) * DM + k0 + cc * 8, Bd + chunk * 8);
    }
  };
  auto comp = [&](const _Float16* As, const _Float16* Bs) {
#pragma unroll
    for (int ks = 0; ks < 2; ++ks) {
      halfx8 af[4], bf[2];
#pragma unroll
      for (int mt = 0; mt < 4; ++mt)
        af[mt] = *(const halfx8*)&As[(wm + mt * 16 + lo) * 64 + (((ks * 4 + quad) ^ lo7) * 8)];
#pragma unroll
      for (int nt = 0; nt < 2; ++nt)
        bf[nt] = *(const halfx8*)&Bs[(wn + nt * 16 + lo) * 64 + (((ks * 4 + quad) ^ lo7) * 8)];
#pragma unroll
      for (int mt = 0; mt < 4; ++mt)
#pragma unroll
        for (int nt = 0; nt < 2; ++nt)
          acc[mt][nt] =
              __builtin_amdgcn_mfma_f32_16x16x32_f16(af[mt], bf[nt], acc[mt][nt], 0, 0, 0);
    }
  };

  stageg(0, A0s, B0s);
  for (int k0 = 0; k0 < DM; k0 += 128) {
    __syncthreads();
    stageg(k0 + 64, A1s, B1s);  // k0+64 <= 960 always valid
    comp(A0s, B0s);
    __syncthreads();
    if (k0 + 128 < DM) stageg(k0 + 128, A0s, B0s);
    comp(A1s, B1s);
  }

  float bv[2];
#pragma unroll
  for (int nt = 0; nt < 2; ++nt) bv[nt] = bias[bn + wn + nt * 16 + lo];
#pragma unroll
  for (int mt = 0; mt < 4; ++mt)
#pragma unroll
    for (int nt = 0; nt < 2; ++nt)
#pragma unroll
      for (int r = 0; r < 4; ++r) {
        int row = bm + wm + mt * 16 + quad * 4 + r;
        int col = bn + wn + nt * 16 + lo;
        Cp[(size_t)row * DM + col] = acc[mt][nt][r] + bv[nt];
      }
}

extern "C" void kernel_launch(void* const* d_in, const int* in_sizes, int n_in,
                              void* d_out, int out_size, void* d_ws, size_t ws_size,
                              hipStream_t stream) {
  const float* in_q = (const float*)d_in[0];
  const float* in_k = (const float*)d_in[1];
  const float* in_v = (const float*)d_in[2];
  const int* mask = (const int*)d_in[3];
  const float* w_q = (const float*)d_in[4];
  const float* w_k = (const float*)d_in[5];
  const float* w_v = (const float*)d_in[6];
  const float* w_o = (const float*)d_in[7];
  const float* b_o = (const float*)d_in[8];
  float* out = (float*)d_out;

  char* ws = (char*)d_ws;
  constexpr size_t WB = (size_t)DM * DM * sizeof(_Float16);
  constexpr size_t MB_ = (size_t)S * S * sizeof(_Float16);
  constexpr size_t TB = (size_t)MROWS * DM * sizeof(_Float16);
  _Float16* wqkv = (_Float16*)(ws);
  _Float16* wto = (_Float16*)(ws + 3 * WB);
  _Float16* Mt = (_Float16*)(ws + 4 * WB);
  char* p = ws + 4 * WB + MB_;
  _Float16* Qf = (_Float16*)(p);
  _Float16* Kf = (_Float16*)(p + TB);
  _Float16* Vt = (_Float16*)(p + 2 * TB);
  _Float16* xq = (_Float16*)(p + 3 * TB);
  _Float16* xk = (_Float16*)(p + 4 * TB);
  _Float16* xv = (_Float16*)(p + 5 * TB);
  _Float16* concat = xq;  // xq dead after qkv_gemm

  prep<<<dim3(12288), 256, 0, stream>>>(w_q, w_k, w_v, w_o, wqkv, wto,
                                        in_q, in_k, in_v, xq, xk, xv, mask, Mt);
  qkv_gemm<<<dim3(24, 32), 256, 0, stream>>>(xq, xk, xv, wqkv, Qf, Kf, Vt);
  attn_kernel<<<dim3(S / 64, NH, BATCH), 128, 0, stream>>>(Qf, Kf, Vt, Mt, concat);
  out_gemm<<<dim3(DM / 64, MROWS / 128), 256, 0, stream>>>(concat, wto, out, b_o);
}